// Round 13
// baseline (1553.111 us; speedup 1.0000x reference)
//
#include <hip/hip_runtime.h>
#include <math.h>

// Problem constants
#define EDIM 300
#define HDIM 512
#define TDIM 100
#define BDIM 256
#define ENC  1024
#define NBLK 256

// Workspace layout (BYTE offsets), ws_size = 268,435,456
#define B_C     0u             // c fp32 [2][256][512]               1,048,576
#define B_HPK   1048576u       // fp16 h packed [2 par][2d*256 rows][64 kb][8hi|8lo]  2,097,152
#define B_WXF   3145728u       // fp16 Wx [2 d][2048 c'][320 k]      2,621,440
#define B_WHF   5767168u       // fp16 WhF [2 d][32 nt][64 frag][512]4,194,304
#define B_CTX   9961472u       // fp32 ctx [256][1024]               1,048,576
#define B_X1    11010048u
#define B_X2    12058624u
#define B_TWH   13107200u      // tail W hi bf16 [3][1024][1024]     6,291,456
#define B_TWL   19398656u      // tail W lo                          6,291,456
#define B_ZX    25690112u      // fp16 zx [2 d][100 t][256 b][2048]  209,715,200 -> ends 235,405,312

typedef __attribute__((ext_vector_type(8))) short bf16x8;
typedef _Float16 f16x8 __attribute__((ext_vector_type(8)));
typedef __attribute__((ext_vector_type(4))) float f32x4;

__device__ __forceinline__ float fast_sigmoid(float x) {
    return 1.0f / (1.0f + __expf(-x));
}
__device__ __forceinline__ float fast_tanh(float x) {
    float t = __expf(2.0f * x);
    return 1.0f - 2.0f / (t + 1.0f);
}
// bf16 helpers (tail GEMM path)
__device__ __forceinline__ unsigned short bf16_rne(float v) {
    unsigned int u = __float_as_uint(v);
    unsigned int r = (u + 0x7fffu + ((u >> 16) & 1u)) >> 16;
    return (unsigned short)r;
}
__device__ __forceinline__ float bf16_to_f(unsigned short h) {
    return __uint_as_float(((unsigned int)h) << 16);
}
__device__ __forceinline__ void split2(float v, unsigned short& hi, unsigned short& lo) {
    hi = bf16_rne(v);
    lo = bf16_rne(v - bf16_to_f(hi));
}
// fp16 helpers (LSTM path)
__device__ __forceinline__ unsigned short f16_bits(float v) {
    _Float16 h = (_Float16)v;
    return *(unsigned short*)&h;
}
__device__ __forceinline__ float f16_val(unsigned short u) {
    _Float16 h = *(_Float16*)&u;
    return (float)h;
}
__device__ __forceinline__ void split_f16(float v, unsigned short& hi, unsigned short& lo) {
    hi = f16_bits(v);
    lo = f16_bits(v - f16_val(hi));
}

__global__ void zero_kernel(float* __restrict__ p, int n) {
    int i = blockIdx.x * blockDim.x + threadIdx.x;
    if (i < n) p[i] = 0.0f;
}

// ---- prep: Wx[cp][320] fp16 (x-part of W, permuted cols c' = G*64+g*16+hl).
__global__ __launch_bounds__(256) void prep_wx(
    const float* __restrict__ WL, const float* __restrict__ WR, char* __restrict__ ws)
{
    __shared__ float tile[64 * 65];
    int bid = blockIdx.x;
    int d = bid / (5 * 32);
    int rem = bid - d * (5 * 32);
    int kt = rem >> 5;                // 0..4
    int ct = rem & 31;
    const int k0 = kt * 64;
    const float* W = d ? WR : WL;
    for (int pass = 0; pass < 16; ++pass) {
        int idx = pass * 256 + threadIdx.x;
        int kk = idx >> 6, c = idx & 63;
        int g = (c >> 4) & 3, hl = c & 15;
        int col = g * HDIM + ct * 16 + hl;
        int kg = k0 + kk;
        tile[kk * 65 + c] = (kg < EDIM) ? W[(size_t)kg * 2048 + col] : 0.0f;
    }
    __syncthreads();
    unsigned short* wx = (unsigned short*)(ws + B_WXF) + (size_t)d * 2048 * 320;
    for (int pass = 0; pass < 16; ++pass) {
        int idx = pass * 256 + threadIdx.x;
        int c = idx >> 6, kk = idx & 63;
        wx[(size_t)(ct * 64 + c) * 320 + k0 + kk] = f16_bits(tile[kk * 65 + c]);
    }
}

// ---- prep: WhF frag-linear: WhF[d][nt][frag][512 ushorts], frag = kh*32+it*4+nf.
__global__ __launch_bounds__(256) void prep_whf(
    const float* __restrict__ WL, const float* __restrict__ WR, char* __restrict__ ws)
{
    __shared__ float tile[64 * 65];
    int bid = blockIdx.x;
    int d = bid >> 8;                 // /256
    int rem = bid & 255;
    int kt = rem >> 5;                // 0..7
    int ct = rem & 31;                // = nt
    const float* W = d ? WR : WL;
    for (int pass = 0; pass < 16; ++pass) {
        int idx = pass * 256 + threadIdx.x;
        int kk = idx >> 6, c = idx & 63;
        int g = (c >> 4) & 3, hl = c & 15;
        int col = g * HDIM + ct * 16 + hl;
        tile[kk * 65 + c] = W[(size_t)(300 + kt * 64 + kk) * 2048 + col];
    }
    __syncthreads();
    unsigned short* dst = (unsigned short*)(ws + B_WHF) + ((size_t)(d * 32 + ct) * 64) * 512;
    #pragma unroll
    for (int p = 0; p < 2; ++p) {
        int item = p * 256 + threadIdx.x;     // 0..511
        int fl = item >> 6;                   // 0..7 = itl*4 + nfl
        int ls = item & 63;
        int itl = fl >> 2, nfl = fl & 3;
        int frag = (kt >> 2) * 32 + ((kt & 3) * 2 + itl) * 4 + nfl;
        __align__(16) unsigned short v[8];
        #pragma unroll
        for (int j = 0; j < 8; ++j)
            v[j] = f16_bits(tile[(itl * 32 + (ls >> 4) * 8 + j) * 65 + nfl * 16 + (ls & 15)]);
        *(uint4*)(dst + (size_t)frag * 512 + ls * 8) = *(uint4*)v;
    }
}

// ---- prep: transpose + split tail weights (bf16 hi/lo). l: 0=TW, 1=HW[0], 2=HW[1].
__global__ __launch_bounds__(256) void prep_w_tail(
    const float* __restrict__ TW, const float* __restrict__ HW, char* __restrict__ ws)
{
    __shared__ float tile[64 * 65];
    int bid = blockIdx.x;
    int l = bid / 256;
    int rem = bid - l * 256;
    int kt = rem >> 4, ct = rem & 15;
    const int k0 = kt * 64, n0 = ct * 64;
    const float* W = (l == 0) ? TW : (HW + (size_t)(l - 1) * ENC * ENC);
    for (int pass = 0; pass < 16; ++pass) {
        int idx = pass * 256 + threadIdx.x;
        int kk = idx >> 6, c = idx & 63;
        tile[kk * 65 + c] = W[(size_t)(k0 + kk) * ENC + n0 + c];
    }
    __syncthreads();
    unsigned short* wh = (unsigned short*)(ws + B_TWH) + (size_t)l * ENC * ENC;
    unsigned short* wl = (unsigned short*)(ws + B_TWL) + (size_t)l * ENC * ENC;
    for (int pass = 0; pass < 16; ++pass) {
        int idx = pass * 256 + threadIdx.x;
        int c = idx >> 6, kk = idx & 63;
        unsigned short hi, lo;
        split2(tile[kk * 65 + c], hi, lo);
        size_t o = (size_t)(n0 + c) * ENC + k0 + kk;
        wh[o] = hi;
        wl[o] = lo;
    }
}

// ---- prep: zx[d][t][b][c'] = x W_x + bias, fp16 (x split hi+lo).
// grid (16 ntile, 16 mg, 2 d) = 512 blocks x 512 thr, 2 blocks/CU, one round.
// W slab (80 KB) loaded to LDS ONCE per block; loop over 25 m-tiles.
// Waves: nh(2, col-half) x ms(4, m-subtile) -> no cross-wave reduce, no barriers
// in the m-loop. Direct (non-staged) stores.
__global__ __launch_bounds__(512, 4) void prep_zx(
    const float* __restrict__ xL, const float* __restrict__ xR,
    const float* __restrict__ bL, const float* __restrict__ bR,
    char* __restrict__ ws)
{
    __shared__ __align__(16) char smem[81920];
    const int ntile = blockIdx.x;         // 0..15
    const int mg    = blockIdx.y;         // 0..15 (each covers 25 m-tiles)
    const int d     = blockIdx.z;
    const int n0    = ntile * 128;
    const float* __restrict__ x    = d ? xR : xL;
    const float* __restrict__ bias = d ? bR : bL;
    const unsigned short* __restrict__ Wxp = (const unsigned short*)(ws + B_WXF) + (size_t)d * 2048 * 320;
    unsigned short* __restrict__ zxd = (unsigned short*)(ws + B_ZX) + (size_t)d * TDIM * BDIM * 2048;

    const int tid = threadIdx.x;
    const int l   = tid & 63;
    const int w   = tid >> 6;
    const int nh  = w >> 2;               // col-half (0..1)
    const int ms  = w & 3;                // m-subtile
    const int fr  = l & 15;
    const int fg  = l >> 4;

    // ---- W slab once: frag = nfg*10 + it (nfg = global n-frag 0..7), 80 x 1KB
    #pragma unroll
    for (int j = 0; j < 10; ++j) {
        int c = j * 512 + tid;            // 0..5119
        int frag = c >> 6, ls = c & 63;
        int nfg = frag / 10, itf = frag - nfg * 10;
        int colp = n0 + nfg * 16 + (ls & 15);
        int kk = itf * 32 + (ls >> 4) * 8;
        *(uint4*)(smem + frag * 1024 + ls * 16) =
            *(const uint4*)(Wxp + (size_t)colp * 320 + kk);
    }
    __syncthreads();

    for (int mi = 0; mi < 25; ++mi) {
        const int m0 = (mg * 25 + mi) * 64;
        const int rowX = m0 + ms * 16 + fr;
        const float* __restrict__ xrow = x + (size_t)rowX * EDIM;

        f32x4 acc[4] = {};
        #pragma unroll
        for (int it = 0; it < 10; ++it) {
            const int kg = it * 32 + fg * 8;
            float4 f4a = (kg + 4 <= EDIM) ? *(const float4*)(xrow + kg) : make_float4(0.f, 0.f, 0.f, 0.f);
            float4 f4b = (kg + 8 <= EDIM) ? *(const float4*)(xrow + kg + 4) : make_float4(0.f, 0.f, 0.f, 0.f);
            __align__(16) unsigned short ahu[8], alu[8];
            float vv[8] = { f4a.x, f4a.y, f4a.z, f4a.w, f4b.x, f4b.y, f4b.z, f4b.w };
            #pragma unroll
            for (int i = 0; i < 8; ++i) {
                unsigned short hi, lo;
                split_f16(vv[i], hi, lo);
                ahu[i] = hi;
                alu[i] = lo;
            }
            const f16x8 ah = *(f16x8*)ahu;
            const f16x8 al = *(f16x8*)alu;
            #pragma unroll
            for (int nf = 0; nf < 4; ++nf) {
                const int frag = (nh * 4 + nf) * 10 + it;
                const f16x8 bv = *(const f16x8*)(smem + (frag << 10) + l * 16);
                acc[nf] = __builtin_amdgcn_mfma_f32_16x16x32_f16(ah, bv, acc[nf], 0, 0, 0);
                acc[nf] = __builtin_amdgcn_mfma_f32_16x16x32_f16(al, bv, acc[nf], 0, 0, 0);
            }
        }

        // ---- epilogue: direct store (no barriers)
        #pragma unroll
        for (int nf = 0; nf < 4; ++nf) {
            const int colp = n0 + nh * 64 + nf * 16 + fr;           // permuted column
            const int G = colp >> 6, g = (colp >> 4) & 3, hl = colp & 15;
            const float bv = bias[g * HDIM + G * 16 + hl];           // original column
            #pragma unroll
            for (int r = 0; r < 4; ++r) {
                const int rm = m0 + ms * 16 + fg * 4 + r;
                const int b = rm / 100;
                const int tt = rm - b * 100;
                zxd[((size_t)(tt * 256 + b)) * 2048 + colp] = f16_bits(acc[nf][r] + bv);
            }
        }
    }
}

// ---- One LSTM timestep, h-part only (K=512). grid 256 x 512 thr.
// Waves: kh(2) x ms(4); wave tile 16m x 64n (nf == gate).
// W slab via async global_load_lds DMA; A (packed fp16 h) preloaded to regs.
__global__ __launch_bounds__(512, 1) void lstm_step_h(
    const int* __restrict__ lenL, const int* __restrict__ lenR,
    char* __restrict__ ws, int t, int par)
{
    __shared__ __align__(16) char smem[65536];

    const int bid   = blockIdx.x;
    const int ntile = (bid & 7) * 4 + ((bid >> 3) & 3);   // 0..31, XCD-aligned
    const int mt    = bid >> 5;                           // 0..7
    const int n0    = ntile * 64;
    const int d     = mt >> 2;
    const int brow  = (mt & 3) * 64;

    const int* __restrict__ len = d ? lenR : lenL;

    float* __restrict__ cbuf = (float*)(ws + B_C);
    const unsigned short* __restrict__ hpk_prev = (const unsigned short*)(ws + B_HPK) + (size_t)par * 524288;
    unsigned short* __restrict__ hpk_next = (unsigned short*)(ws + B_HPK) + (size_t)(par ^ 1) * 524288;
    const unsigned short* __restrict__ WhF = (const unsigned short*)(ws + B_WHF);
    const unsigned short* __restrict__ zxd = (const unsigned short*)(ws + B_ZX) + (size_t)d * TDIM * BDIM * 2048;
    float* __restrict__ ctx = (float*)(ws + B_CTX);

    const int tid = threadIdx.x;
    const int l   = tid & 63;
    const int w   = tid >> 6;
    const int kh  = w >> 2;
    const int ms  = w & 3;
    const int fr  = l & 15;
    const int fg  = l >> 4;

    // ---- W slab: async DMA, 8 x 1KB chunks per wave (issued first, in flight)
    {
        const unsigned short* __restrict__ wsrc = WhF + ((size_t)(d * 32 + ntile) * 64) * 512;
        #pragma unroll
        for (int j = 0; j < 8; ++j) {
            const unsigned short* g = wsrc + (size_t)(j * 512 + tid) * 8;
            char* ldst = smem + ((size_t)(j * 512 + (w << 6)) * 16);
            __builtin_amdgcn_global_load_lds(
                (const __attribute__((address_space(1))) void*)(const void*)g,
                (__attribute__((address_space(3))) void*)(void*)ldst, 16, 0, 0);
        }
    }

    // ---- A: preload all 8 iterations (packed rows: 1024 shorts/row)
    const int arow = d * BDIM + brow + ms * 16 + fr;
    const unsigned short* __restrict__ abase = hpk_prev + (size_t)arow * 1024;
    uint4 aph[8], apl[8];
    #pragma unroll
    for (int it = 0; it < 8; ++it) {
        const int kb = kh * 32 + it * 4 + fg;            // k/8
        aph[it] = *(const uint4*)(abase + kb * 16);
        apl[it] = *(const uint4*)(abase + kb * 16 + 8);
    }

    // ---- epilogue operand prefetch (kh==0 threads)
    const int hcol = ntile * 16 + fr;
    const int row0 = brow + ms * 16 + fg * 4;            // batch rows (within dir)
    const int4 len4 = *(const int4*)(len + row0);
    float c_arr[4];
    unsigned short zraw[16];
    if (kh == 0) {
        const size_t cb = (size_t)(d * BDIM + row0) * HDIM + hcol;
        c_arr[0] = cbuf[cb];
        c_arr[1] = cbuf[cb + HDIM];
        c_arr[2] = cbuf[cb + 2 * HDIM];
        c_arr[3] = cbuf[cb + 3 * HDIM];
        const unsigned short* zb = zxd + ((size_t)(t * 256 + row0)) * 2048 + n0 + fr;
        #pragma unroll
        for (int r = 0; r < 4; ++r)
            #pragma unroll
            for (int nf = 0; nf < 4; ++nf)
                zraw[r * 4 + nf] = zb[r * 2048 + nf * 16];
    }
    __syncthreads();    // drains vmcnt (W DMA + A loads) and barriers

    // ---- MFMA loop: registers + LDS only
    f32x4 acc[4] = {};
    #pragma unroll
    for (int it = 0; it < 8; ++it) {
        const f16x8 ah = *(const f16x8*)&aph[it];
        const f16x8 al = *(const f16x8*)&apl[it];
        #pragma unroll
        for (int nf = 0; nf < 4; ++nf) {
            const f16x8 bv = *(const f16x8*)(smem + ((kh * 32 + it * 4 + nf) << 10) + l * 16);
            acc[nf] = __builtin_amdgcn_mfma_f32_16x16x32_f16(ah, bv, acc[nf], 0, 0, 0);
            acc[nf] = __builtin_amdgcn_mfma_f32_16x16x32_f16(al, bv, acc[nf], 0, 0, 0);
        }
    }

    // ---- cross-half reduce (red overlays dead W slab)
    __syncthreads();
    float* red = (float*)smem;            // 64 x 65 floats
    if (kh == 1) {
        #pragma unroll
        for (int nf = 0; nf < 4; ++nf)
            #pragma unroll
            for (int r = 0; r < 4; ++r)
                red[(ms * 16 + fg * 4 + r) * 65 + nf * 16 + fr] = acc[nf][r];
    }
    __syncthreads();
    if (kh == 0) {
        const int lens[4] = { len4.x, len4.y, len4.z, len4.w };
        #pragma unroll
        for (int r = 0; r < 4; ++r) {
            const int row = row0 + r;
            const int rb = (ms * 16 + fg * 4 + r) * 65;
            const float iv = acc[0][r] + red[rb + 0 * 16 + fr] + f16_val(zraw[r * 4 + 0]);
            const float jv = acc[1][r] + red[rb + 1 * 16 + fr] + f16_val(zraw[r * 4 + 1]);
            const float fv = acc[2][r] + red[rb + 2 * 16 + fr] + f16_val(zraw[r * 4 + 2]);
            const float ov = acc[3][r] + red[rb + 3 * 16 + fr] + f16_val(zraw[r * 4 + 3]);
            const float c_new = c_arr[r] * fast_sigmoid(fv + 1.0f)
                              + fast_sigmoid(iv) * fast_tanh(jv);
            const float h_new = fast_tanh(c_new) * fast_sigmoid(ov);
            const size_t cidx = (size_t)(d * BDIM + row) * HDIM + hcol;
            cbuf[cidx] = c_new;
            unsigned short hh, hl2;
            split_f16(h_new, hh, hl2);
            const size_t hidx = (size_t)(d * BDIM + row) * 1024 + (hcol >> 3) * 16 + (hcol & 7);
            hpk_next[hidx] = hh;
            hpk_next[hidx + 8] = hl2;
            if (t == lens[r] - 1) {
                ctx[(size_t)row * (2 * HDIM) + d * HDIM + hcol] = h_new;
            }
        }
    }
}

// ---- tail GEMM: C = relu(A @ W), A [256,1024] fp32, W pre-split bf16 [1024 n][1024 k].
#define TL_AS_HI(hf) ((hf) * 5120)
#define TL_AS_LO(hf) (10240 + (hf) * 5120)
#define TL_BS_HI(hf) (20480 + (hf) * 5120)
#define TL_BS_LO(hf) (30720 + (hf) * 5120)

__global__ __launch_bounds__(512, 2) void gemm_relu_mfma(
    const float* __restrict__ A, const unsigned short* __restrict__ Wh,
    const unsigned short* __restrict__ Wl, float* __restrict__ C)
{
    const int ntile = blockIdx.x & 15;
    const int mt    = blockIdx.x >> 4;
    const int n0    = ntile * 64;
    const int m0    = mt * 64;

    __shared__ __align__(16) char smem[40960];

    const int tid  = threadIdx.x;
    const int l    = tid & 63;
    const int w    = tid >> 6;
    const int kh   = w >> 2;
    const int ms   = w & 3;
    const int fr   = l & 15;
    const int fg   = l >> 4;
    const int arow = tid >> 3;
    const int q    = (tid & 7) * 4;

    f32x4 acc[4] = {};

    for (int it = 0; it < 16; ++it) {
        #pragma unroll
        for (int hf = 0; hf < 2; ++hf) {
            const int kg = hf * 512 + it * 32 + q;
            const float4 v = *(const float4*)(A + (size_t)(m0 + arow) * ENC + kg);
            ushort4 vh, vl;
            split2(v.x, vh.x, vl.x);
            split2(v.y, vh.y, vl.y);
            split2(v.z, vh.z, vl.z);
            split2(v.w, vh.w, vl.w);
            *(ushort4*)(smem + TL_AS_HI(hf) + (arow * 40 + q) * 2) = vh;
            *(ushort4*)(smem + TL_AS_LO(hf) + (arow * 40 + q) * 2) = vl;
            const size_t wo = (size_t)(n0 + arow) * ENC + kg;
            *(ushort4*)(smem + TL_BS_HI(hf) + (arow * 40 + q) * 2) = *(const ushort4*)(Wh + wo);
            *(ushort4*)(smem + TL_BS_LO(hf) + (arow * 40 + q) * 2) = *(const ushort4*)(Wl + wo);
        }
        __syncthreads();
        const int aoff = ((ms * 16 + fr) * 40 + fg * 8) * 2;
        const bf16x8 ah = *(const bf16x8*)(smem + TL_AS_HI(kh) + aoff);
        const bf16x8 al = *(const bf16x8*)(smem + TL_AS_LO(kh) + aoff);
        #pragma unroll
        for (int nf = 0; nf < 4; ++nf) {
            const int boff = ((nf * 16 + fr) * 40 + fg * 8) * 2;
            const bf16x8 bh = *(const bf16x8*)(smem + TL_BS_HI(kh) + boff);
            const bf16x8 bl = *(const bf16x8*)(smem + TL_BS_LO(kh) + boff);
            acc[nf] = __builtin_amdgcn_mfma_f32_16x16x32_bf16(ah, bh, acc[nf], 0, 0, 0);
            acc[nf] = __builtin_amdgcn_mfma_f32_16x16x32_bf16(ah, bl, acc[nf], 0, 0, 0);
            acc[nf] = __builtin_amdgcn_mfma_f32_16x16x32_bf16(al, bh, acc[nf], 0, 0, 0);
        }
        __syncthreads();
    }

    float* red = (float*)smem;
    if (kh == 1) {
        #pragma unroll
        for (int nf = 0; nf < 4; ++nf)
            #pragma unroll
            for (int r = 0; r < 4; ++r)
                red[(ms * 16 + fg * 4 + r) * 65 + nf * 16 + fr] = acc[nf][r];
    }
    __syncthreads();
    if (kh == 0) {
        #pragma unroll
        for (int nf = 0; nf < 4; ++nf) {
            #pragma unroll
            for (int r = 0; r < 4; ++r) {
                float v = acc[nf][r] + red[(ms * 16 + fg * 4 + r) * 65 + nf * 16 + fr];
                v = v > 0.f ? v : 0.f;
                const int row = m0 + ms * 16 + fg * 4 + r;
                C[(size_t)row * ENC + n0 + nf * 16 + fr] = v;
            }
        }
    }
}

extern "C" void kernel_launch(void* const* d_in, const int* in_sizes, int n_in,
                              void* d_out, int out_size, void* d_ws, size_t ws_size,
                              hipStream_t stream) {
    const float* xL   = (const float*)d_in[0];
    const int*   lenL = (const int*)  d_in[1];
    const float* xR   = (const float*)d_in[2];
    const int*   lenR = (const int*)  d_in[3];
    const float* WL   = (const float*)d_in[4];
    const float* bL   = (const float*)d_in[5];
    const float* WR   = (const float*)d_in[6];
    const float* bR   = (const float*)d_in[7];
    const float* TW   = (const float*)d_in[8];
    const float* HW   = (const float*)d_in[9];
    char* ws   = (char*)d_ws;
    float* out = (float*)d_out;

    // zero c + hpk (both parities): first 3 MB
    zero_kernel<<<3072, 256, 0, stream>>>((float*)ws, 786432);
    prep_wx<<<320, 256, 0, stream>>>(WL, WR, ws);
    prep_whf<<<512, 256, 0, stream>>>(WL, WR, ws);
    prep_w_tail<<<768, 256, 0, stream>>>(TW, HW, ws);
    prep_zx<<<dim3(16, 16, 2), 512, 0, stream>>>(xL, xR, bL, bR, ws);

    for (int t = 0; t < TDIM; ++t) {
        lstm_step_h<<<NBLK, 512, 0, stream>>>(lenL, lenR, ws, t, t & 1);
    }

    float* ctx = (float*)(ws + B_CTX);
    float* x1  = (float*)(ws + B_X1);
    float* x2  = (float*)(ws + B_X2);
    const unsigned short* twh = (const unsigned short*)(ws + B_TWH);
    const unsigned short* twl = (const unsigned short*)(ws + B_TWL);
    gemm_relu_mfma<<<64, 512, 0, stream>>>(ctx, twh,                twl,                x1);
    gemm_relu_mfma<<<64, 512, 0, stream>>>(x1,  twh + 1024 * 1024, twl + 1024 * 1024,  x2);
    gemm_relu_mfma<<<64, 512, 0, stream>>>(x2,  twh + 2048 * 1024, twl + 2048 * 1024,  out);
}

// Round 14
// 1296.169 us; speedup vs baseline: 1.1982x; 1.1982x over previous
//
#include <hip/hip_runtime.h>
#include <math.h>

// Problem constants
#define EDIM 300
#define HDIM 512
#define TDIM 100
#define BDIM 256
#define ENC  1024
#define NBLK 256

// Workspace layout (BYTE offsets), ws_size = 268,435,456
#define B_C     0u             // c fp32 [2][256][512]               1,048,576
#define B_HPK   1048576u       // fp16 h packed [2 par][2d*256 rows][64 kb][8hi|8lo]  2,097,152
#define B_WXF   3145728u       // fp16 WxF frag-linear [2 d][16 nt][80 frag][512]    2,621,440
#define B_WHF   5767168u       // fp16 WhF [2 d][32 nt][64 frag][512]4,194,304
#define B_CTX   9961472u       // fp32 ctx [256][1024]               1,048,576
#define B_X1    11010048u
#define B_X2    12058624u
#define B_TWH   13107200u      // tail W hi bf16 [3][1024][1024]     6,291,456
#define B_TWL   19398656u      // tail W lo                          6,291,456
#define B_ZX    25690112u      // fp16 zx [2 d][100 t][256 b][2048]  209,715,200 -> ends 235,405,312

typedef __attribute__((ext_vector_type(8))) short bf16x8;
typedef _Float16 f16x8 __attribute__((ext_vector_type(8)));
typedef __attribute__((ext_vector_type(4))) float f32x4;

__device__ __forceinline__ float fast_sigmoid(float x) {
    return 1.0f / (1.0f + __expf(-x));
}
__device__ __forceinline__ float fast_tanh(float x) {
    float t = __expf(2.0f * x);
    return 1.0f - 2.0f / (t + 1.0f);
}
// bf16 helpers (tail GEMM path)
__device__ __forceinline__ unsigned short bf16_rne(float v) {
    unsigned int u = __float_as_uint(v);
    unsigned int r = (u + 0x7fffu + ((u >> 16) & 1u)) >> 16;
    return (unsigned short)r;
}
__device__ __forceinline__ float bf16_to_f(unsigned short h) {
    return __uint_as_float(((unsigned int)h) << 16);
}
__device__ __forceinline__ void split2(float v, unsigned short& hi, unsigned short& lo) {
    hi = bf16_rne(v);
    lo = bf16_rne(v - bf16_to_f(hi));
}
// fp16 helpers (LSTM path)
__device__ __forceinline__ unsigned short f16_bits(float v) {
    _Float16 h = (_Float16)v;
    return *(unsigned short*)&h;
}
__device__ __forceinline__ float f16_val(unsigned short u) {
    _Float16 h = *(_Float16*)&u;
    return (float)h;
}
__device__ __forceinline__ void split_f16(float v, unsigned short& hi, unsigned short& lo) {
    hi = f16_bits(v);
    lo = f16_bits(v - f16_val(hi));
}

__global__ void zero_kernel(float* __restrict__ p, int n) {
    int i = blockIdx.x * blockDim.x + threadIdx.x;
    if (i < n) p[i] = 0.0f;
}

// ---- prep: WxF frag-linear: WxF[d][nt16][80 frag][512 ushorts],
// frag = kh*40 + it*8 + nf; content[ls*8+j] = Wx_f16[k=kh*160+it*32+(ls>>4)*8+j]
// [colp = nt*128 + nf*16 + (ls&15)]; Wx[k][colp] = W[k][col(colp)] (0 for k>=300).
// grid 2 d x 10 ktt x 16 nt = 320 blocks, 256 thr.
__global__ __launch_bounds__(256) void prep_wxf(
    const float* __restrict__ WL, const float* __restrict__ WR, char* __restrict__ ws)
{
    __shared__ float tile[32 * 130];
    int bid = blockIdx.x;
    int d = bid / 160;
    int rem = bid - d * 160;
    int ktt = rem >> 4;               // 0..9
    int nt  = rem & 15;
    const int kh  = ktt / 5;
    const int itt = ktt - kh * 5;
    const int k0  = kh * 160 + itt * 32;
    const float* W = d ? WR : WL;
    for (int pass = 0; pass < 16; ++pass) {
        int idx = pass * 256 + threadIdx.x;   // 0..4095
        int kk = idx >> 7, c = idx & 127;
        int colp = nt * 128 + c;
        int G = colp >> 6, g = (colp >> 4) & 3, hl = colp & 15;
        int col = g * HDIM + G * 16 + hl;
        int kg = k0 + kk;
        tile[kk * 130 + c] = (kg < EDIM) ? W[(size_t)kg * 2048 + col] : 0.0f;
    }
    __syncthreads();
    unsigned short* slab = (unsigned short*)(ws + B_WXF) + (size_t)(d * 16 + nt) * 80 * 512;
    #pragma unroll
    for (int p = 0; p < 2; ++p) {
        int item = p * 256 + threadIdx.x;     // 0..511
        int nf = item >> 6, ls = item & 63;
        __align__(16) unsigned short v[8];
        #pragma unroll
        for (int j = 0; j < 8; ++j)
            v[j] = f16_bits(tile[((ls >> 4) * 8 + j) * 130 + nf * 16 + (ls & 15)]);
        *(uint4*)(slab + (size_t)(kh * 40 + itt * 8 + nf) * 512 + ls * 8) = *(uint4*)v;
    }
}

// ---- prep: WhF frag-linear: WhF[d][nt][frag][512 ushorts], frag = kh*32+it*4+nf.
__global__ __launch_bounds__(256) void prep_whf(
    const float* __restrict__ WL, const float* __restrict__ WR, char* __restrict__ ws)
{
    __shared__ float tile[64 * 65];
    int bid = blockIdx.x;
    int d = bid >> 8;                 // /256
    int rem = bid & 255;
    int kt = rem >> 5;                // 0..7
    int ct = rem & 31;                // = nt
    const float* W = d ? WR : WL;
    for (int pass = 0; pass < 16; ++pass) {
        int idx = pass * 256 + threadIdx.x;
        int kk = idx >> 6, c = idx & 63;
        int g = (c >> 4) & 3, hl = c & 15;
        int col = g * HDIM + ct * 16 + hl;
        tile[kk * 65 + c] = W[(size_t)(300 + kt * 64 + kk) * 2048 + col];
    }
    __syncthreads();
    unsigned short* dst = (unsigned short*)(ws + B_WHF) + ((size_t)(d * 32 + ct) * 64) * 512;
    #pragma unroll
    for (int p = 0; p < 2; ++p) {
        int item = p * 256 + threadIdx.x;     // 0..511
        int fl = item >> 6;                   // 0..7 = itl*4 + nfl
        int ls = item & 63;
        int itl = fl >> 2, nfl = fl & 3;
        int frag = (kt >> 2) * 32 + ((kt & 3) * 2 + itl) * 4 + nfl;
        __align__(16) unsigned short v[8];
        #pragma unroll
        for (int j = 0; j < 8; ++j)
            v[j] = f16_bits(tile[(itl * 32 + (ls >> 4) * 8 + j) * 65 + nfl * 16 + (ls & 15)]);
        *(uint4*)(dst + (size_t)frag * 512 + ls * 8) = *(uint4*)v;
    }
}

// ---- prep: transpose + split tail weights (bf16 hi/lo). l: 0=TW, 1=HW[0], 2=HW[1].
__global__ __launch_bounds__(256) void prep_w_tail(
    const float* __restrict__ TW, const float* __restrict__ HW, char* __restrict__ ws)
{
    __shared__ float tile[64 * 65];
    int bid = blockIdx.x;
    int l = bid / 256;
    int rem = bid - l * 256;
    int kt = rem >> 4, ct = rem & 15;
    const int k0 = kt * 64, n0 = ct * 64;
    const float* W = (l == 0) ? TW : (HW + (size_t)(l - 1) * ENC * ENC);
    for (int pass = 0; pass < 16; ++pass) {
        int idx = pass * 256 + threadIdx.x;
        int kk = idx >> 6, c = idx & 63;
        tile[kk * 65 + c] = W[(size_t)(k0 + kk) * ENC + n0 + c];
    }
    __syncthreads();
    unsigned short* wh = (unsigned short*)(ws + B_TWH) + (size_t)l * ENC * ENC;
    unsigned short* wl = (unsigned short*)(ws + B_TWL) + (size_t)l * ENC * ENC;
    for (int pass = 0; pass < 16; ++pass) {
        int idx = pass * 256 + threadIdx.x;
        int c = idx >> 6, kk = idx & 63;
        unsigned short hi, lo;
        split2(tile[kk * 65 + c], hi, lo);
        size_t o = (size_t)(n0 + c) * ENC + k0 + kk;
        wh[o] = hi;
        wl[o] = lo;
    }
}

// ---- prep: zx[d][t][b][c'] = x W_x + bias, fp16 (x split hi+lo).
// grid (16 ntile, 400 mtile, 2 d) x 512 thr. Block tile 64m x 128n, K=320.
// W slab (80 KB) via async global_load_lds DMA from frag-linear WxF; all x
// loads register-preloaded before the single barrier. Staged coalesced writes.
__global__ __launch_bounds__(512, 4) void prep_zx(
    const float* __restrict__ xL, const float* __restrict__ xR,
    const float* __restrict__ bL, const float* __restrict__ bR,
    char* __restrict__ ws)
{
    __shared__ __align__(16) char smem[81920];
    const int ntile = blockIdx.x;         // 0..15
    const int m0    = blockIdx.y * 64;    // rows = b*100+t flat, 0..25599
    const int d     = blockIdx.z;
    const float* __restrict__ x    = d ? xR : xL;
    const float* __restrict__ bias = d ? bR : bL;
    const unsigned short* __restrict__ WxF = (const unsigned short*)(ws + B_WXF);
    unsigned short* __restrict__ zxd = (unsigned short*)(ws + B_ZX) + (size_t)d * TDIM * BDIM * 2048;

    const int tid = threadIdx.x;
    const int l   = tid & 63;
    const int w   = tid >> 6;
    const int kh  = w >> 2;
    const int ms  = w & 3;
    const int fr  = l & 15;
    const int fg  = l >> 4;

    // ---- W slab: async DMA (identity copy of frag-linear slab), 80 x 1KB
    {
        const unsigned short* __restrict__ wsrc = WxF + (size_t)(d * 16 + ntile) * 80 * 512;
        #pragma unroll
        for (int j = 0; j < 10; ++j) {
            const unsigned short* g = wsrc + (size_t)(j * 512 + tid) * 8;
            char* ldst = smem + ((size_t)(j * 512 + (w << 6)) * 16);
            __builtin_amdgcn_global_load_lds(
                (const __attribute__((address_space(1))) void*)(const void*)g,
                (__attribute__((address_space(3))) void*)(void*)ldst, 16, 0, 0);
        }
    }

    // ---- x: preload all 5 iterations to registers (latency under W DMA)
    const int rowX = m0 + ms * 16 + fr;
    const float* __restrict__ xrow = x + (size_t)rowX * EDIM;
    const int kb = kh * 160 + fg * 8;
    float4 xa[5], xb[5];
    #pragma unroll
    for (int it = 0; it < 5; ++it) {
        const int kg = kb + it * 32;
        xa[it] = (kg + 4 <= EDIM) ? *(const float4*)(xrow + kg)     : make_float4(0.f, 0.f, 0.f, 0.f);
        xb[it] = (kg + 8 <= EDIM) ? *(const float4*)(xrow + kg + 4) : make_float4(0.f, 0.f, 0.f, 0.f);
    }
    __syncthreads();    // drains W DMA (vmcnt) + barriers

    f32x4 acc[8] = {};
    #pragma unroll
    for (int it = 0; it < 5; ++it) {
        __align__(16) unsigned short ahu[8], alu[8];
        float vv[8] = { xa[it].x, xa[it].y, xa[it].z, xa[it].w,
                        xb[it].x, xb[it].y, xb[it].z, xb[it].w };
        #pragma unroll
        for (int i = 0; i < 8; ++i) {
            unsigned short hi, lo;
            split_f16(vv[i], hi, lo);
            ahu[i] = hi;
            alu[i] = lo;
        }
        const f16x8 ah = *(f16x8*)ahu;
        const f16x8 al = *(f16x8*)alu;
        #pragma unroll
        for (int nf = 0; nf < 8; ++nf) {
            const f16x8 bv = *(const f16x8*)(smem + ((kh * 40 + it * 8 + nf) << 10) + l * 16);
            acc[nf] = __builtin_amdgcn_mfma_f32_16x16x32_f16(ah, bv, acc[nf], 0, 0, 0);
            acc[nf] = __builtin_amdgcn_mfma_f32_16x16x32_f16(al, bv, acc[nf], 0, 0, 0);
        }
    }

    __syncthreads();
    float* red = (float*)smem;                          // 64 x 132 f32 = 33,792 B
    unsigned short* outT = (unsigned short*)(smem + 49152);  // 64 x 128 fp16 = 16 KB
    if (kh == 1) {
        #pragma unroll
        for (int nf = 0; nf < 8; ++nf)
            #pragma unroll
            for (int r = 0; r < 4; ++r)
                red[(ms * 16 + fg * 4 + r) * 132 + nf * 16 + fr] = acc[nf][r];
    }
    __syncthreads();
    if (kh == 0) {
        #pragma unroll
        for (int nf = 0; nf < 8; ++nf) {
            const int col = (nf & 3) * HDIM + (ntile * 2 + (nf >> 2)) * 16 + fr;  // original column
            const float bv = bias[col];
            #pragma unroll
            for (int r = 0; r < 4; ++r) {
                float v = acc[nf][r] + red[(ms * 16 + fg * 4 + r) * 132 + nf * 16 + fr] + bv;
                outT[(ms * 16 + fg * 4 + r) * 128 + nf * 16 + fr] = f16_bits(v);
            }
        }
    }
    __syncthreads();
    // coalesced copy: 64 rows x 256 B -> zx[t][b] layout
    {
        int row = tid >> 3, seg = tid & 7;
        int rm = m0 + row;
        int b = rm / 100;
        int tt = rm - b * 100;
        unsigned short* dstrow = zxd + ((size_t)(tt * 256 + b)) * 2048 + ntile * 128 + seg * 16;
        const unsigned short* s = outT + row * 128 + seg * 16;
        *(uint4*)(dstrow)     = *(const uint4*)(s);
        *(uint4*)(dstrow + 8) = *(const uint4*)(s + 8);
    }
}

// ---- One LSTM timestep, h-part only (K=512). grid 256 x 512 thr.
// Waves: kh(2) x ms(4); wave tile 16m x 64n (nf == gate).
// W slab via async global_load_lds DMA; A (packed fp16 h) preloaded to regs.
__global__ __launch_bounds__(512, 1) void lstm_step_h(
    const int* __restrict__ lenL, const int* __restrict__ lenR,
    char* __restrict__ ws, int t, int par)
{
    __shared__ __align__(16) char smem[65536];

    const int bid   = blockIdx.x;
    const int ntile = (bid & 7) * 4 + ((bid >> 3) & 3);   // 0..31, XCD-aligned
    const int mt    = bid >> 5;                           // 0..7
    const int n0    = ntile * 64;
    const int d     = mt >> 2;
    const int brow  = (mt & 3) * 64;

    const int* __restrict__ len = d ? lenR : lenL;

    float* __restrict__ cbuf = (float*)(ws + B_C);
    const unsigned short* __restrict__ hpk_prev = (const unsigned short*)(ws + B_HPK) + (size_t)par * 524288;
    unsigned short* __restrict__ hpk_next = (unsigned short*)(ws + B_HPK) + (size_t)(par ^ 1) * 524288;
    const unsigned short* __restrict__ WhF = (const unsigned short*)(ws + B_WHF);
    const unsigned short* __restrict__ zxd = (const unsigned short*)(ws + B_ZX) + (size_t)d * TDIM * BDIM * 2048;
    float* __restrict__ ctx = (float*)(ws + B_CTX);

    const int tid = threadIdx.x;
    const int l   = tid & 63;
    const int w   = tid >> 6;
    const int kh  = w >> 2;
    const int ms  = w & 3;
    const int fr  = l & 15;
    const int fg  = l >> 4;

    // ---- W slab: async DMA, 8 x 1KB chunks per wave (issued first, in flight)
    {
        const unsigned short* __restrict__ wsrc = WhF + ((size_t)(d * 32 + ntile) * 64) * 512;
        #pragma unroll
        for (int j = 0; j < 8; ++j) {
            const unsigned short* g = wsrc + (size_t)(j * 512 + tid) * 8;
            char* ldst = smem + ((size_t)(j * 512 + (w << 6)) * 16);
            __builtin_amdgcn_global_load_lds(
                (const __attribute__((address_space(1))) void*)(const void*)g,
                (__attribute__((address_space(3))) void*)(void*)ldst, 16, 0, 0);
        }
    }

    // ---- A: preload all 8 iterations (packed rows: 1024 shorts/row)
    const int arow = d * BDIM + brow + ms * 16 + fr;
    const unsigned short* __restrict__ abase = hpk_prev + (size_t)arow * 1024;
    uint4 aph[8], apl[8];
    #pragma unroll
    for (int it = 0; it < 8; ++it) {
        const int kb = kh * 32 + it * 4 + fg;            // k/8
        aph[it] = *(const uint4*)(abase + kb * 16);
        apl[it] = *(const uint4*)(abase + kb * 16 + 8);
    }

    // ---- epilogue operand prefetch (kh==0 threads)
    const int hcol = ntile * 16 + fr;
    const int row0 = brow + ms * 16 + fg * 4;            // batch rows (within dir)
    const int4 len4 = *(const int4*)(len + row0);
    float c_arr[4];
    unsigned short zraw[16];
    if (kh == 0) {
        const size_t cb = (size_t)(d * BDIM + row0) * HDIM + hcol;
        c_arr[0] = cbuf[cb];
        c_arr[1] = cbuf[cb + HDIM];
        c_arr[2] = cbuf[cb + 2 * HDIM];
        c_arr[3] = cbuf[cb + 3 * HDIM];
        const unsigned short* zb = zxd + ((size_t)(t * 256 + row0)) * 2048 + n0 + fr;
        #pragma unroll
        for (int r = 0; r < 4; ++r)
            #pragma unroll
            for (int nf = 0; nf < 4; ++nf)
                zraw[r * 4 + nf] = zb[r * 2048 + nf * 16];
    }
    __syncthreads();    // drains vmcnt (W DMA + A loads) and barriers

    // ---- MFMA loop: registers + LDS only
    f32x4 acc[4] = {};
    #pragma unroll
    for (int it = 0; it < 8; ++it) {
        const f16x8 ah = *(const f16x8*)&aph[it];
        const f16x8 al = *(const f16x8*)&apl[it];
        #pragma unroll
        for (int nf = 0; nf < 4; ++nf) {
            const f16x8 bv = *(const f16x8*)(smem + ((kh * 32 + it * 4 + nf) << 10) + l * 16);
            acc[nf] = __builtin_amdgcn_mfma_f32_16x16x32_f16(ah, bv, acc[nf], 0, 0, 0);
            acc[nf] = __builtin_amdgcn_mfma_f32_16x16x32_f16(al, bv, acc[nf], 0, 0, 0);
        }
    }

    // ---- cross-half reduce (red overlays dead W slab)
    __syncthreads();
    float* red = (float*)smem;            // 64 x 65 floats
    if (kh == 1) {
        #pragma unroll
        for (int nf = 0; nf < 4; ++nf)
            #pragma unroll
            for (int r = 0; r < 4; ++r)
                red[(ms * 16 + fg * 4 + r) * 65 + nf * 16 + fr] = acc[nf][r];
    }
    __syncthreads();
    if (kh == 0) {
        const int lens[4] = { len4.x, len4.y, len4.z, len4.w };
        #pragma unroll
        for (int r = 0; r < 4; ++r) {
            const int row = row0 + r;
            const int rb = (ms * 16 + fg * 4 + r) * 65;
            const float iv = acc[0][r] + red[rb + 0 * 16 + fr] + f16_val(zraw[r * 4 + 0]);
            const float jv = acc[1][r] + red[rb + 1 * 16 + fr] + f16_val(zraw[r * 4 + 1]);
            const float fv = acc[2][r] + red[rb + 2 * 16 + fr] + f16_val(zraw[r * 4 + 2]);
            const float ov = acc[3][r] + red[rb + 3 * 16 + fr] + f16_val(zraw[r * 4 + 3]);
            const float c_new = c_arr[r] * fast_sigmoid(fv + 1.0f)
                              + fast_sigmoid(iv) * fast_tanh(jv);
            const float h_new = fast_tanh(c_new) * fast_sigmoid(ov);
            const size_t cidx = (size_t)(d * BDIM + row) * HDIM + hcol;
            cbuf[cidx] = c_new;
            unsigned short hh, hl2;
            split_f16(h_new, hh, hl2);
            const size_t hidx = (size_t)(d * BDIM + row) * 1024 + (hcol >> 3) * 16 + (hcol & 7);
            hpk_next[hidx] = hh;
            hpk_next[hidx + 8] = hl2;
            if (t == lens[r] - 1) {
                ctx[(size_t)row * (2 * HDIM) + d * HDIM + hcol] = h_new;
            }
        }
    }
}

// ---- tail GEMM: C = relu(A @ W), A [256,1024] fp32, W pre-split bf16 [1024 n][1024 k].
#define TL_AS_HI(hf) ((hf) * 5120)
#define TL_AS_LO(hf) (10240 + (hf) * 5120)
#define TL_BS_HI(hf) (20480 + (hf) * 5120)
#define TL_BS_LO(hf) (30720 + (hf) * 5120)

__global__ __launch_bounds__(512, 2) void gemm_relu_mfma(
    const float* __restrict__ A, const unsigned short* __restrict__ Wh,
    const unsigned short* __restrict__ Wl, float* __restrict__ C)
{
    const int ntile = blockIdx.x & 15;
    const int mt    = blockIdx.x >> 4;
    const int n0    = ntile * 64;
    const int m0    = mt * 64;

    __shared__ __align__(16) char smem[40960];

    const int tid  = threadIdx.x;
    const int l    = tid & 63;
    const int w    = tid >> 6;
    const int kh   = w >> 2;
    const int ms   = w & 3;
    const int fr   = l & 15;
    const int fg   = l >> 4;
    const int arow = tid >> 3;
    const int q    = (tid & 7) * 4;

    f32x4 acc[4] = {};

    for (int it = 0; it < 16; ++it) {
        #pragma unroll
        for (int hf = 0; hf < 2; ++hf) {
            const int kg = hf * 512 + it * 32 + q;
            const float4 v = *(const float4*)(A + (size_t)(m0 + arow) * ENC + kg);
            ushort4 vh, vl;
            split2(v.x, vh.x, vl.x);
            split2(v.y, vh.y, vl.y);
            split2(v.z, vh.z, vl.z);
            split2(v.w, vh.w, vl.w);
            *(ushort4*)(smem + TL_AS_HI(hf) + (arow * 40 + q) * 2) = vh;
            *(ushort4*)(smem + TL_AS_LO(hf) + (arow * 40 + q) * 2) = vl;
            const size_t wo = (size_t)(n0 + arow) * ENC + kg;
            *(ushort4*)(smem + TL_BS_HI(hf) + (arow * 40 + q) * 2) = *(const ushort4*)(Wh + wo);
            *(ushort4*)(smem + TL_BS_LO(hf) + (arow * 40 + q) * 2) = *(const ushort4*)(Wl + wo);
        }
        __syncthreads();
        const int aoff = ((ms * 16 + fr) * 40 + fg * 8) * 2;
        const bf16x8 ah = *(const bf16x8*)(smem + TL_AS_HI(kh) + aoff);
        const bf16x8 al = *(const bf16x8*)(smem + TL_AS_LO(kh) + aoff);
        #pragma unroll
        for (int nf = 0; nf < 4; ++nf) {
            const int boff = ((nf * 16 + fr) * 40 + fg * 8) * 2;
            const bf16x8 bh = *(const bf16x8*)(smem + TL_BS_HI(kh) + boff);
            const bf16x8 bl = *(const bf16x8*)(smem + TL_BS_LO(kh) + boff);
            acc[nf] = __builtin_amdgcn_mfma_f32_16x16x32_bf16(ah, bh, acc[nf], 0, 0, 0);
            acc[nf] = __builtin_amdgcn_mfma_f32_16x16x32_bf16(ah, bl, acc[nf], 0, 0, 0);
            acc[nf] = __builtin_amdgcn_mfma_f32_16x16x32_bf16(al, bh, acc[nf], 0, 0, 0);
        }
        __syncthreads();
    }

    float* red = (float*)smem;
    if (kh == 1) {
        #pragma unroll
        for (int nf = 0; nf < 4; ++nf)
            #pragma unroll
            for (int r = 0; r < 4; ++r)
                red[(ms * 16 + fg * 4 + r) * 65 + nf * 16 + fr] = acc[nf][r];
    }
    __syncthreads();
    if (kh == 0) {
        #pragma unroll
        for (int nf = 0; nf < 4; ++nf) {
            #pragma unroll
            for (int r = 0; r < 4; ++r) {
                float v = acc[nf][r] + red[(ms * 16 + fg * 4 + r) * 65 + nf * 16 + fr];
                v = v > 0.f ? v : 0.f;
                const int row = m0 + ms * 16 + fg * 4 + r;
                C[(size_t)row * ENC + n0 + nf * 16 + fr] = v;
            }
        }
    }
}

extern "C" void kernel_launch(void* const* d_in, const int* in_sizes, int n_in,
                              void* d_out, int out_size, void* d_ws, size_t ws_size,
                              hipStream_t stream) {
    const float* xL   = (const float*)d_in[0];
    const int*   lenL = (const int*)  d_in[1];
    const float* xR   = (const float*)d_in[2];
    const int*   lenR = (const int*)  d_in[3];
    const float* WL   = (const float*)d_in[4];
    const float* bL   = (const float*)d_in[5];
    const float* WR   = (const float*)d_in[6];
    const float* bR   = (const float*)d_in[7];
    const float* TW   = (const float*)d_in[8];
    const float* HW   = (const float*)d_in[9];
    char* ws   = (char*)d_ws;
    float* out = (float*)d_out;

    // zero c + hpk (both parities): first 3 MB
    zero_kernel<<<3072, 256, 0, stream>>>((float*)ws, 786432);
    prep_wxf<<<320, 256, 0, stream>>>(WL, WR, ws);
    prep_whf<<<512, 256, 0, stream>>>(WL, WR, ws);
    prep_w_tail<<<768, 256, 0, stream>>>(TW, HW, ws);
    prep_zx<<<dim3(16, 400, 2), 512, 0, stream>>>(xL, xR, bL, bR, ws);

    for (int t = 0; t < TDIM; ++t) {
        lstm_step_h<<<NBLK, 512, 0, stream>>>(lenL, lenR, ws, t, t & 1);
    }

    float* ctx = (float*)(ws + B_CTX);
    float* x1  = (float*)(ws + B_X1);
    float* x2  = (float*)(ws + B_X2);
    const unsigned short* twh = (const unsigned short*)(ws + B_TWH);
    const unsigned short* twl = (const unsigned short*)(ws + B_TWL);
    gemm_relu_mfma<<<64, 512, 0, stream>>>(ctx, twh,                twl,                x1);
    gemm_relu_mfma<<<64, 512, 0, stream>>>(x1,  twh + 1024 * 1024, twl + 1024 * 1024,  x2);
    gemm_relu_mfma<<<64, 512, 0, stream>>>(x2,  twh + 2048 * 1024, twl + 2048 * 1024,  out);
}

// Round 15
// 1295.386 us; speedup vs baseline: 1.1990x; 1.0006x over previous
//
#include <hip/hip_runtime.h>
#include <math.h>

// Problem constants
#define EDIM 300
#define HDIM 512
#define TDIM 100
#define BDIM 256
#define ENC  1024

// Workspace layout (BYTE offsets), ws_size = 268,435,456
#define B_C     0u             // c fp32 [2][256][512]               1,048,576
#define B_HPK   1048576u       // fp16 h packed [2 par][2d*256 rows][64 kb][8hi|8lo]  2,097,152
#define B_WXF   3145728u       // fp16 WxF frag-linear [2 d][16 nt][80 frag][512]    2,621,440
#define B_WHF   5767168u       // fp16 WhF [2 d][32 nt][64 frag][512]4,194,304
#define B_CTX   9961472u       // fp32 ctx [256][1024]               1,048,576
#define B_X1    11010048u
#define B_X2    12058624u
#define B_TWH   13107200u      // tail W hi bf16 [3][1024][1024]     6,291,456
#define B_TWL   19398656u      // tail W lo                          6,291,456
#define B_ZX    25690112u      // fp16 zx [2 d][100 t][256 b][2048]  209,715,200 -> ends 235,405,312

typedef __attribute__((ext_vector_type(8))) short bf16x8;
typedef _Float16 f16x8 __attribute__((ext_vector_type(8)));
typedef __attribute__((ext_vector_type(4))) float f32x4;

__device__ __forceinline__ float fast_sigmoid(float x) {
    return 1.0f / (1.0f + __expf(-x));
}
__device__ __forceinline__ float fast_tanh(float x) {
    float t = __expf(2.0f * x);
    return 1.0f - 2.0f / (t + 1.0f);
}
// bf16 helpers (tail GEMM path)
__device__ __forceinline__ unsigned short bf16_rne(float v) {
    unsigned int u = __float_as_uint(v);
    unsigned int r = (u + 0x7fffu + ((u >> 16) & 1u)) >> 16;
    return (unsigned short)r;
}
__device__ __forceinline__ float bf16_to_f(unsigned short h) {
    return __uint_as_float(((unsigned int)h) << 16);
}
__device__ __forceinline__ void split2(float v, unsigned short& hi, unsigned short& lo) {
    hi = bf16_rne(v);
    lo = bf16_rne(v - bf16_to_f(hi));
}
// fp16 helpers (LSTM path)
__device__ __forceinline__ unsigned short f16_bits(float v) {
    _Float16 h = (_Float16)v;
    return *(unsigned short*)&h;
}
__device__ __forceinline__ float f16_val(unsigned short u) {
    _Float16 h = *(_Float16*)&u;
    return (float)h;
}
__device__ __forceinline__ void split_f16(float v, unsigned short& hi, unsigned short& lo) {
    hi = f16_bits(v);
    lo = f16_bits(v - f16_val(hi));
}

__global__ void zero_kernel(float* __restrict__ p, int n) {
    int i = blockIdx.x * blockDim.x + threadIdx.x;
    if (i < n) p[i] = 0.0f;
}

// ---- prep: WxF frag-linear: WxF[d][nt16][80 frag][512 ushorts],
// frag = kh*40 + it*8 + nf; content[ls*8+j] = Wx_f16[k=kh*160+it*32+(ls>>4)*8+j]
// [colp = nt*128 + nf*16 + (ls&15)]; Wx[k][colp] = W[k][col(colp)] (0 for k>=300).
__global__ __launch_bounds__(256) void prep_wxf(
    const float* __restrict__ WL, const float* __restrict__ WR, char* __restrict__ ws)
{
    __shared__ float tile[32 * 130];
    int bid = blockIdx.x;
    int d = bid / 160;
    int rem = bid - d * 160;
    int ktt = rem >> 4;               // 0..9
    int nt  = rem & 15;
    const int kh  = ktt / 5;
    const int itt = ktt - kh * 5;
    const int k0  = kh * 160 + itt * 32;
    const float* W = d ? WR : WL;
    for (int pass = 0; pass < 16; ++pass) {
        int idx = pass * 256 + threadIdx.x;   // 0..4095
        int kk = idx >> 7, c = idx & 127;
        int colp = nt * 128 + c;
        int G = colp >> 6, g = (colp >> 4) & 3, hl = colp & 15;
        int col = g * HDIM + G * 16 + hl;
        int kg = k0 + kk;
        tile[kk * 130 + c] = (kg < EDIM) ? W[(size_t)kg * 2048 + col] : 0.0f;
    }
    __syncthreads();
    unsigned short* slab = (unsigned short*)(ws + B_WXF) + (size_t)(d * 16 + nt) * 80 * 512;
    #pragma unroll
    for (int p = 0; p < 2; ++p) {
        int item = p * 256 + threadIdx.x;     // 0..511
        int nf = item >> 6, ls = item & 63;
        __align__(16) unsigned short v[8];
        #pragma unroll
        for (int j = 0; j < 8; ++j)
            v[j] = f16_bits(tile[((ls >> 4) * 8 + j) * 130 + nf * 16 + (ls & 15)]);
        *(uint4*)(slab + (size_t)(kh * 40 + itt * 8 + nf) * 512 + ls * 8) = *(uint4*)v;
    }
}

// ---- prep: WhF frag-linear: WhF[d][nt][frag][512 ushorts], frag = kh*32+it*4+nf.
__global__ __launch_bounds__(256) void prep_whf(
    const float* __restrict__ WL, const float* __restrict__ WR, char* __restrict__ ws)
{
    __shared__ float tile[64 * 65];
    int bid = blockIdx.x;
    int d = bid >> 8;                 // /256
    int rem = bid & 255;
    int kt = rem >> 5;                // 0..7
    int ct = rem & 31;                // = nt
    const float* W = d ? WR : WL;
    for (int pass = 0; pass < 16; ++pass) {
        int idx = pass * 256 + threadIdx.x;
        int kk = idx >> 6, c = idx & 63;
        int g = (c >> 4) & 3, hl = c & 15;
        int col = g * HDIM + ct * 16 + hl;
        tile[kk * 65 + c] = W[(size_t)(300 + kt * 64 + kk) * 2048 + col];
    }
    __syncthreads();
    unsigned short* dst = (unsigned short*)(ws + B_WHF) + ((size_t)(d * 32 + ct) * 64) * 512;
    #pragma unroll
    for (int p = 0; p < 2; ++p) {
        int item = p * 256 + threadIdx.x;     // 0..511
        int fl = item >> 6;                   // 0..7 = itl*4 + nfl
        int ls = item & 63;
        int itl = fl >> 2, nfl = fl & 3;
        int frag = (kt >> 2) * 32 + ((kt & 3) * 2 + itl) * 4 + nfl;
        __align__(16) unsigned short v[8];
        #pragma unroll
        for (int j = 0; j < 8; ++j)
            v[j] = f16_bits(tile[(itl * 32 + (ls >> 4) * 8 + j) * 65 + nfl * 16 + (ls & 15)]);
        *(uint4*)(dst + (size_t)frag * 512 + ls * 8) = *(uint4*)v;
    }
}

// ---- prep: transpose + split tail weights (bf16 hi/lo). l: 0=TW, 1=HW[0], 2=HW[1].
__global__ __launch_bounds__(256) void prep_w_tail(
    const float* __restrict__ TW, const float* __restrict__ HW, char* __restrict__ ws)
{
    __shared__ float tile[64 * 65];
    int bid = blockIdx.x;
    int l = bid / 256;
    int rem = bid - l * 256;
    int kt = rem >> 4, ct = rem & 15;
    const int k0 = kt * 64, n0 = ct * 64;
    const float* W = (l == 0) ? TW : (HW + (size_t)(l - 1) * ENC * ENC);
    for (int pass = 0; pass < 16; ++pass) {
        int idx = pass * 256 + threadIdx.x;
        int kk = idx >> 6, c = idx & 63;
        tile[kk * 65 + c] = W[(size_t)(k0 + kk) * ENC + n0 + c];
    }
    __syncthreads();
    unsigned short* wh = (unsigned short*)(ws + B_TWH) + (size_t)l * ENC * ENC;
    unsigned short* wl = (unsigned short*)(ws + B_TWL) + (size_t)l * ENC * ENC;
    for (int pass = 0; pass < 16; ++pass) {
        int idx = pass * 256 + threadIdx.x;
        int c = idx >> 6, kk = idx & 63;
        unsigned short hi, lo;
        split2(tile[kk * 65 + c], hi, lo);
        size_t o = (size_t)(n0 + c) * ENC + k0 + kk;
        wh[o] = hi;
        wl[o] = lo;
    }
}

// ---- prep: zx[d][t][b][c'] = x W_x + bias, fp16 (x split hi+lo).
// grid (16 ntile, 400 mtile, 2 d) x 512 thr. Block tile 64m x 128n, K=320.
// W slab via async global_load_lds DMA; x register-preloaded.
// Store pattern: each store INSTRUCTION covers full 128B lines (8 lanes x 16B
// contiguous) -> no read-for-ownership fetch on the zx write stream.
__global__ __launch_bounds__(512, 4) void prep_zx(
    const float* __restrict__ xL, const float* __restrict__ xR,
    const float* __restrict__ bL, const float* __restrict__ bR,
    char* __restrict__ ws)
{
    __shared__ __align__(16) char smem[81920];
    const int ntile = blockIdx.x;         // 0..15
    const int m0    = blockIdx.y * 64;    // rows = b*100+t flat, 0..25599
    const int d     = blockIdx.z;
    const float* __restrict__ x    = d ? xR : xL;
    const float* __restrict__ bias = d ? bR : bL;
    const unsigned short* __restrict__ WxF = (const unsigned short*)(ws + B_WXF);
    unsigned short* __restrict__ zxd = (unsigned short*)(ws + B_ZX) + (size_t)d * TDIM * BDIM * 2048;

    const int tid = threadIdx.x;
    const int l   = tid & 63;
    const int w   = tid >> 6;
    const int kh  = w >> 2;
    const int ms  = w & 3;
    const int fr  = l & 15;
    const int fg  = l >> 4;

    // ---- W slab: async DMA (identity copy of frag-linear slab), 80 x 1KB
    {
        const unsigned short* __restrict__ wsrc = WxF + (size_t)(d * 16 + ntile) * 80 * 512;
        #pragma unroll
        for (int j = 0; j < 10; ++j) {
            const unsigned short* g = wsrc + (size_t)(j * 512 + tid) * 8;
            char* ldst = smem + ((size_t)(j * 512 + (w << 6)) * 16);
            __builtin_amdgcn_global_load_lds(
                (const __attribute__((address_space(1))) void*)(const void*)g,
                (__attribute__((address_space(3))) void*)(void*)ldst, 16, 0, 0);
        }
    }

    // ---- x: preload all 5 iterations to registers (latency under W DMA)
    const int rowX = m0 + ms * 16 + fr;
    const float* __restrict__ xrow = x + (size_t)rowX * EDIM;
    const int kb = kh * 160 + fg * 8;
    float4 xa[5], xb[5];
    #pragma unroll
    for (int it = 0; it < 5; ++it) {
        const int kg = kb + it * 32;
        xa[it] = (kg + 4 <= EDIM) ? *(const float4*)(xrow + kg)     : make_float4(0.f, 0.f, 0.f, 0.f);
        xb[it] = (kg + 8 <= EDIM) ? *(const float4*)(xrow + kg + 4) : make_float4(0.f, 0.f, 0.f, 0.f);
    }
    __syncthreads();    // drains W DMA (vmcnt) + barriers

    f32x4 acc[8] = {};
    #pragma unroll
    for (int it = 0; it < 5; ++it) {
        __align__(16) unsigned short ahu[8], alu[8];
        float vv[8] = { xa[it].x, xa[it].y, xa[it].z, xa[it].w,
                        xb[it].x, xb[it].y, xb[it].z, xb[it].w };
        #pragma unroll
        for (int i = 0; i < 8; ++i) {
            unsigned short hi, lo;
            split_f16(vv[i], hi, lo);
            ahu[i] = hi;
            alu[i] = lo;
        }
        const f16x8 ah = *(f16x8*)ahu;
        const f16x8 al = *(f16x8*)alu;
        #pragma unroll
        for (int nf = 0; nf < 8; ++nf) {
            const f16x8 bv = *(const f16x8*)(smem + ((kh * 40 + it * 8 + nf) << 10) + l * 16);
            acc[nf] = __builtin_amdgcn_mfma_f32_16x16x32_f16(ah, bv, acc[nf], 0, 0, 0);
            acc[nf] = __builtin_amdgcn_mfma_f32_16x16x32_f16(al, bv, acc[nf], 0, 0, 0);
        }
    }

    __syncthreads();
    float* red = (float*)smem;                          // 64 x 132 f32 = 33,792 B
    unsigned short* outT = (unsigned short*)(smem + 49152);  // 64 x 128 fp16 = 16 KB
    if (kh == 1) {
        #pragma unroll
        for (int nf = 0; nf < 8; ++nf)
            #pragma unroll
            for (int r = 0; r < 4; ++r)
                red[(ms * 16 + fg * 4 + r) * 132 + nf * 16 + fr] = acc[nf][r];
    }
    __syncthreads();
    if (kh == 0) {
        #pragma unroll
        for (int nf = 0; nf < 8; ++nf) {
            const int col = (nf & 3) * HDIM + (ntile * 2 + (nf >> 2)) * 16 + fr;  // original column
            const float bv = bias[col];
            #pragma unroll
            for (int r = 0; r < 4; ++r) {
                float v = acc[nf][r] + red[(ms * 16 + fg * 4 + r) * 132 + nf * 16 + fr] + bv;
                outT[(ms * 16 + fg * 4 + r) * 128 + nf * 16 + fr] = f16_bits(v);
            }
        }
    }
    __syncthreads();
    // coalesced copy, full-line store instructions:
    // instr 1: lanes seg=0..7 cover bytes 0..127 of the row segment; instr 2: 128..255.
    {
        int row = tid >> 3, seg = tid & 7;
        int rm = m0 + row;
        int b = rm / 100;
        int tt = rm - b * 100;
        unsigned short* dstrow = zxd + ((size_t)(tt * 256 + b)) * 2048 + ntile * 128;
        const unsigned short* s = outT + row * 128;
        *(uint4*)(dstrow + seg * 8)      = *(const uint4*)(s + seg * 8);
        *(uint4*)(dstrow + 64 + seg * 8) = *(const uint4*)(s + 64 + seg * 8);
    }
}

// ---- One LSTM timestep, h-part only (K=512). grid 512 blocks x 256 thr
// (4 waves: kh(2) x ms(2)), 2 blocks/CU (2 x 64KB LDS = 128KB) so one block's
// W-DMA/A-loads overlap the other's MFMA/epilogue. Block tile 32m x 64n.
__global__ __launch_bounds__(256, 2) void lstm_step_h(
    const int* __restrict__ lenL, const int* __restrict__ lenR,
    char* __restrict__ ws, int t, int par)
{
    __shared__ __align__(16) char smem[65536];

    const int bid   = blockIdx.x;
    const int ntile = (bid & 7) * 4 + ((bid >> 3) & 3);   // 0..31, XCD-aligned
    const int mth   = bid >> 5;                           // 0..15 (32-row groups)
    const int n0    = ntile * 64;
    const int d     = mth >> 3;
    const int brow  = (mth & 7) * 32;

    const int* __restrict__ len = d ? lenR : lenL;

    float* __restrict__ cbuf = (float*)(ws + B_C);
    const unsigned short* __restrict__ hpk_prev = (const unsigned short*)(ws + B_HPK) + (size_t)par * 524288;
    unsigned short* __restrict__ hpk_next = (unsigned short*)(ws + B_HPK) + (size_t)(par ^ 1) * 524288;
    const unsigned short* __restrict__ WhF = (const unsigned short*)(ws + B_WHF);
    const unsigned short* __restrict__ zxd = (const unsigned short*)(ws + B_ZX) + (size_t)d * TDIM * BDIM * 2048;
    float* __restrict__ ctx = (float*)(ws + B_CTX);

    const int tid = threadIdx.x;
    const int l   = tid & 63;
    const int w   = tid >> 6;             // 0..3
    const int kh  = w >> 1;               // K-half
    const int ms  = w & 1;                // 16-row half
    const int fr  = l & 15;
    const int fg  = l >> 4;

    // ---- W slab: async DMA, 64KB in 16 x 4KB rounds (issued first, in flight)
    {
        const unsigned short* __restrict__ wsrc = WhF + ((size_t)(d * 32 + ntile) * 64) * 512;
        #pragma unroll
        for (int j = 0; j < 16; ++j) {
            const unsigned short* g = wsrc + (size_t)(j * 256 + tid) * 8;
            char* ldst = smem + ((size_t)(j * 256 + (w << 6)) * 16);
            __builtin_amdgcn_global_load_lds(
                (const __attribute__((address_space(1))) void*)(const void*)g,
                (__attribute__((address_space(3))) void*)(void*)ldst, 16, 0, 0);
        }
    }

    // ---- A: preload all 8 iterations (packed rows: 1024 shorts/row)
    const int arow = d * BDIM + brow + ms * 16 + fr;
    const unsigned short* __restrict__ abase = hpk_prev + (size_t)arow * 1024;
    uint4 aph[8], apl[8];
    #pragma unroll
    for (int it = 0; it < 8; ++it) {
        const int kb = kh * 32 + it * 4 + fg;            // k/8
        aph[it] = *(const uint4*)(abase + kb * 16);
        apl[it] = *(const uint4*)(abase + kb * 16 + 8);
    }

    // ---- epilogue operand prefetch (kh==0 waves)
    const int hcol = ntile * 16 + fr;
    const int row0 = brow + ms * 16 + fg * 4;            // batch rows (within dir)
    const int4 len4 = *(const int4*)(len + row0);
    float c_arr[4];
    unsigned short zraw[16];
    if (kh == 0) {
        const size_t cb = (size_t)(d * BDIM + row0) * HDIM + hcol;
        c_arr[0] = cbuf[cb];
        c_arr[1] = cbuf[cb + HDIM];
        c_arr[2] = cbuf[cb + 2 * HDIM];
        c_arr[3] = cbuf[cb + 3 * HDIM];
        const unsigned short* zb = zxd + ((size_t)(t * 256 + row0)) * 2048 + n0 + fr;
        #pragma unroll
        for (int r = 0; r < 4; ++r)
            #pragma unroll
            for (int nf = 0; nf < 4; ++nf)
                zraw[r * 4 + nf] = zb[r * 2048 + nf * 16];
    }
    __syncthreads();    // drains vmcnt (W DMA + A loads) and barriers

    // ---- MFMA loop: registers + LDS only (frag addressing unchanged)
    f32x4 acc[4] = {};
    #pragma unroll
    for (int it = 0; it < 8; ++it) {
        const f16x8 ah = *(const f16x8*)&aph[it];
        const f16x8 al = *(const f16x8*)&apl[it];
        #pragma unroll
        for (int nf = 0; nf < 4; ++nf) {
            const f16x8 bv = *(const f16x8*)(smem + ((kh * 32 + it * 4 + nf) << 10) + l * 16);
            acc[nf] = __builtin_amdgcn_mfma_f32_16x16x32_f16(ah, bv, acc[nf], 0, 0, 0);
            acc[nf] = __builtin_amdgcn_mfma_f32_16x16x32_f16(al, bv, acc[nf], 0, 0, 0);
        }
    }

    // ---- cross-half reduce (red overlays dead W slab; 32 x 65 floats)
    __syncthreads();
    float* red = (float*)smem;
    if (kh == 1) {
        #pragma unroll
        for (int nf = 0; nf < 4; ++nf)
            #pragma unroll
            for (int r = 0; r < 4; ++r)
                red[(ms * 16 + fg * 4 + r) * 65 + nf * 16 + fr] = acc[nf][r];
    }
    __syncthreads();
    if (kh == 0) {
        const int lens[4] = { len4.x, len4.y, len4.z, len4.w };
        #pragma unroll
        for (int r = 0; r < 4; ++r) {
            const int row = row0 + r;
            const int rb = (ms * 16 + fg * 4 + r) * 65;
            const float iv = acc[0][r] + red[rb + 0 * 16 + fr] + f16_val(zraw[r * 4 + 0]);
            const float jv = acc[1][r] + red[rb + 1 * 16 + fr] + f16_val(zraw[r * 4 + 1]);
            const float fv = acc[2][r] + red[rb + 2 * 16 + fr] + f16_val(zraw[r * 4 + 2]);
            const float ov = acc[3][r] + red[rb + 3 * 16 + fr] + f16_val(zraw[r * 4 + 3]);
            const float c_new = c_arr[r] * fast_sigmoid(fv + 1.0f)
                              + fast_sigmoid(iv) * fast_tanh(jv);
            const float h_new = fast_tanh(c_new) * fast_sigmoid(ov);
            const size_t cidx = (size_t)(d * BDIM + row) * HDIM + hcol;
            cbuf[cidx] = c_new;
            unsigned short hh, hl2;
            split_f16(h_new, hh, hl2);
            const size_t hidx = (size_t)(d * BDIM + row) * 1024 + (hcol >> 3) * 16 + (hcol & 7);
            hpk_next[hidx] = hh;
            hpk_next[hidx + 8] = hl2;
            if (t == lens[r] - 1) {
                ctx[(size_t)row * (2 * HDIM) + d * HDIM + hcol] = h_new;
            }
        }
    }
}

// ---- tail GEMM: C = relu(A @ W), A [256,1024] fp32, W pre-split bf16 [1024 n][1024 k].
#define TL_AS_HI(hf) ((hf) * 5120)
#define TL_AS_LO(hf) (10240 + (hf) * 5120)
#define TL_BS_HI(hf) (20480 + (hf) * 5120)
#define TL_BS_LO(hf) (30720 + (hf) * 5120)

__global__ __launch_bounds__(512, 2) void gemm_relu_mfma(
    const float* __restrict__ A, const unsigned short* __restrict__ Wh,
    const unsigned short* __restrict__ Wl, float* __restrict__ C)
{
    const int ntile = blockIdx.x & 15;
    const int mt    = blockIdx.x >> 4;
    const int n0    = ntile * 64;
    const int m0    = mt * 64;

    __shared__ __align__(16) char smem[40960];

    const int tid  = threadIdx.x;
    const int l    = tid & 63;
    const int w    = tid >> 6;
    const int kh   = w >> 2;
    const int ms   = w & 3;
    const int fr   = l & 15;
    const int fg   = l >> 4;
    const int arow = tid >> 3;
    const int q    = (tid & 7) * 4;

    f32x4 acc[4] = {};

    for (int it = 0; it < 16; ++it) {
        #pragma unroll
        for (int hf = 0; hf < 2; ++hf) {
            const int kg = hf * 512 + it * 32 + q;
            const float4 v = *(const float4*)(A + (size_t)(m0 + arow) * ENC + kg);
            ushort4 vh, vl;
            split2(v.x, vh.x, vl.x);
            split2(v.y, vh.y, vl.y);
            split2(v.z, vh.z, vl.z);
            split2(v.w, vh.w, vl.w);
            *(ushort4*)(smem + TL_AS_HI(hf) + (arow * 40 + q) * 2) = vh;
            *(ushort4*)(smem + TL_AS_LO(hf) + (arow * 40 + q) * 2) = vl;
            const size_t wo = (size_t)(n0 + arow) * ENC + kg;
            *(ushort4*)(smem + TL_BS_HI(hf) + (arow * 40 + q) * 2) = *(const ushort4*)(Wh + wo);
            *(ushort4*)(smem + TL_BS_LO(hf) + (arow * 40 + q) * 2) = *(const ushort4*)(Wl + wo);
        }
        __syncthreads();
        const int aoff = ((ms * 16 + fr) * 40 + fg * 8) * 2;
        const bf16x8 ah = *(const bf16x8*)(smem + TL_AS_HI(kh) + aoff);
        const bf16x8 al = *(const bf16x8*)(smem + TL_AS_LO(kh) + aoff);
        #pragma unroll
        for (int nf = 0; nf < 4; ++nf) {
            const int boff = ((nf * 16 + fr) * 40 + fg * 8) * 2;
            const bf16x8 bh = *(const bf16x8*)(smem + TL_BS_HI(kh) + boff);
            const bf16x8 bl = *(const bf16x8*)(smem + TL_BS_LO(kh) + boff);
            acc[nf] = __builtin_amdgcn_mfma_f32_16x16x32_bf16(ah, bh, acc[nf], 0, 0, 0);
            acc[nf] = __builtin_amdgcn_mfma_f32_16x16x32_bf16(ah, bl, acc[nf], 0, 0, 0);
            acc[nf] = __builtin_amdgcn_mfma_f32_16x16x32_bf16(al, bh, acc[nf], 0, 0, 0);
        }
        __syncthreads();
    }

    float* red = (float*)smem;
    if (kh == 1) {
        #pragma unroll
        for (int nf = 0; nf < 4; ++nf)
            #pragma unroll
            for (int r = 0; r < 4; ++r)
                red[(ms * 16 + fg * 4 + r) * 65 + nf * 16 + fr] = acc[nf][r];
    }
    __syncthreads();
    if (kh == 0) {
        #pragma unroll
        for (int nf = 0; nf < 4; ++nf) {
            #pragma unroll
            for (int r = 0; r < 4; ++r) {
                float v = acc[nf][r] + red[(ms * 16 + fg * 4 + r) * 65 + nf * 16 + fr];
                v = v > 0.f ? v : 0.f;
                const int row = m0 + ms * 16 + fg * 4 + r;
                C[(size_t)row * ENC + n0 + nf * 16 + fr] = v;
            }
        }
    }
}

extern "C" void kernel_launch(void* const* d_in, const int* in_sizes, int n_in,
                              void* d_out, int out_size, void* d_ws, size_t ws_size,
                              hipStream_t stream) {
    const float* xL   = (const float*)d_in[0];
    const int*   lenL = (const int*)  d_in[1];
    const float* xR   = (const float*)d_in[2];
    const int*   lenR = (const int*)  d_in[3];
    const float* WL   = (const float*)d_in[4];
    const float* bL   = (const float*)d_in[5];
    const float* WR   = (const float*)d_in[6];
    const float* bR   = (const float*)d_in[7];
    const float* TW   = (const float*)d_in[8];
    const float* HW   = (const float*)d_in[9];
    char* ws   = (char*)d_ws;
    float* out = (float*)d_out;

    // zero c + hpk (both parities): first 3 MB
    zero_kernel<<<3072, 256, 0, stream>>>((float*)ws, 786432);
    prep_wxf<<<320, 256, 0, stream>>>(WL, WR, ws);
    prep_whf<<<512, 256, 0, stream>>>(WL, WR, ws);
    prep_w_tail<<<768, 256, 0, stream>>>(TW, HW, ws);
    prep_zx<<<dim3(16, 400, 2), 512, 0, stream>>>(xL, xR, bL, bR, ws);

    for (int t = 0; t < TDIM; ++t) {
        lstm_step_h<<<512, 256, 0, stream>>>(lenL, lenR, ws, t, t & 1);
    }

    float* ctx = (float*)(ws + B_CTX);
    float* x1  = (float*)(ws + B_X1);
    float* x2  = (float*)(ws + B_X2);
    const unsigned short* twh = (const unsigned short*)(ws + B_TWH);
    const unsigned short* twl = (const unsigned short*)(ws + B_TWL);
    gemm_relu_mfma<<<64, 512, 0, stream>>>(ctx, twh,                twl,                x1);
    gemm_relu_mfma<<<64, 512, 0, stream>>>(x1,  twh + 1024 * 1024, twl + 1024 * 1024,  x2);
    gemm_relu_mfma<<<64, 512, 0, stream>>>(x2,  twh + 2048 * 1024, twl + 2048 * 1024,  out);
}